// Round 18
// baseline (955.597 us; speedup 1.0000x reference)
//
#include <hip/hip_runtime.h>

#define HDIM 256
#define NHB 256          // chunks for histogram/fill (chunk = nE/NHB = 6250)
#define NBINB 50048      // bins rounded to 64: covers nN <= 50048 nodes (u8 bins)
#define NBINW (NBINB/4)  // 12512 u32 words = 50 KB LDS
#define NBAND 16         // src band = src >> 12
#define LDP 40

typedef __attribute__((ext_vector_type(8))) short short8v;
typedef __attribute__((ext_vector_type(4))) short short4v;
typedef __attribute__((ext_vector_type(4))) float floatx4;

static __device__ __forceinline__ unsigned short f2bf(float f) {
    union { float f; unsigned u; } c; c.f = f;
    unsigned u = c.u;
    unsigned r = u + 0x7FFFu + ((u >> 16) & 1u);   // RNE
    return (unsigned short)(r >> 16);
}
static __device__ __forceinline__ float bf2f(unsigned short h) {
    union { unsigned u; float f; } c; c.u = ((unsigned)h) << 16;
    return c.f;
}

// ---------------- histogram: per-block private LDS u8 hist, no global atomics ----------------

__global__ __launch_bounds__(512) void hist_k(const int* __restrict__ src, const int* __restrict__ dst,
                                              unsigned int* __restrict__ degS, unsigned int* __restrict__ cntS,
                                              int nE) {
    __shared__ unsigned int h8[NBINW];
    const int tid = threadIdx.x;
    const int isDst = blockIdx.x >= NHB;
    const int bb = isDst ? blockIdx.x - NHB : blockIdx.x;
    const int* __restrict__ arr = isDst ? dst : src;
    unsigned int* __restrict__ outS = isDst ? cntS : degS;

    for (int i = tid; i < NBINW; i += 512) h8[i] = 0u;
    __syncthreads();
    const int chunk = (nE + NHB - 1) / NHB;
    const int e0 = bb * chunk;
    const int e1 = min(e0 + chunk, nE);
    for (int e = e0 + tid; e < e1; e += 512) {
        int n = arr[e];
        atomicAdd(&h8[n >> 2], 1u << ((n & 3) << 3));
    }
    __syncthreads();
    unsigned int* __restrict__ row = outS + (size_t)bb * NBINW;
    for (int i = tid; i < NBINW; i += 512) row[i] = h8[i];
}

// ---------------- reduce + scan1 ----------------

__global__ __launch_bounds__(256) void reduce_k(const unsigned char* __restrict__ degS,
                                                unsigned char* __restrict__ cntS,
                                                float* __restrict__ dis, int* __restrict__ tmp,
                                                int* __restrict__ bsums, int nN) {
    __shared__ int s[256];
    const int t = threadIdx.x;
    const int n = blockIdx.x * 256 + t;
    int run = 0;
    if (n < nN) {
        int d = 0;
        #pragma unroll 8
        for (int b = 0; b < NHB; ++b) d += degS[(size_t)b * NBINB + n];
        dis[n] = (d > 0) ? (1.0f / sqrtf((float)d)) : 0.0f;
        unsigned r = 0;
        #pragma unroll 4
        for (int b = 0; b < NHB; ++b) {
            size_t o = (size_t)b * NBINB + n;
            unsigned c = cntS[o];
            cntS[o] = (unsigned char)r;
            r += c;
        }
        run = (int)r;
    }
    s[t] = run; __syncthreads();
    #pragma unroll
    for (int off = 1; off < 256; off <<= 1) {
        int x = (t >= off) ? s[t - off] : 0;
        __syncthreads();
        s[t] += x;
        __syncthreads();
    }
    if (n < nN) tmp[n] = s[t];
    if (t == 255) bsums[blockIdx.x] = s[255];
}

// ---------------- scan3 (+ scan2 folded) ----------------

__global__ __launch_bounds__(256) void scan3_k(const int* __restrict__ tmp, const int* __restrict__ bsums,
                                               int* __restrict__ offs, int nN, int nE, int nb) {
    __shared__ int s[256];
    const int t = threadIdx.x;
    int v = (t < nb) ? bsums[t] : 0;
    s[t] = v; __syncthreads();
    #pragma unroll
    for (int off = 1; off < 256; off <<= 1) {
        int x = (t >= off) ? s[t - off] : 0;
        __syncthreads();
        s[t] += x;
        __syncthreads();
    }
    const int base = (blockIdx.x > 0) ? s[blockIdx.x - 1] : 0;
    __syncthreads();
    const int i = blockIdx.x * 256 + t;
    if (i < nN) {
        int prev = (t > 0) ? tmp[i - 1] : 0;
        offs[i] = base + prev;
    }
    if (i == nN - 1) offs[nN] = nE;
}

// ---------------- fill ----------------

__global__ __launch_bounds__(512) void fill_k(const int* __restrict__ src, const int* __restrict__ dst,
                                              const float* __restrict__ dis, const int* __restrict__ offs,
                                              const unsigned int* __restrict__ cntS,
                                              int2* __restrict__ csr, int nE) {
    __shared__ unsigned int cur8[NBINW];
    const int tid = threadIdx.x;
    const int bb = blockIdx.x;
    const unsigned int* __restrict__ baseRow = cntS + (size_t)bb * NBINW;
    for (int i = tid; i < NBINW; i += 512) cur8[i] = baseRow[i];
    __syncthreads();
    const int chunk = (nE + NHB - 1) / NHB;
    const int e0 = bb * chunk;
    const int e1 = min(e0 + chunk, nE);
    for (int e = e0 + tid; e < e1; e += 512) {
        int s = src[e], d = dst[e];
        unsigned sh = (unsigned)(d & 3) << 3;
        unsigned old = atomicAdd(&cur8[d >> 2], 1u << sh);
        unsigned c = (old >> sh) & 0xFFu;
        int p = offs[d] + (int)c;
        float w = -dis[s] * dis[d];
        csr[p] = make_int2(s, __float_as_int(w));
    }
}

// ---------------- weight splits ----------------

struct WPtrs { const float* w[7]; };
__global__ __launch_bounds__(256) void wsplit_all_k(WPtrs ws, unsigned short* __restrict__ base) {
    int wi = blockIdx.x >> 6;
    int idx = (blockIdx.x & 63) * 256 + threadIdx.x;
    const float* w = ws.w[wi];
    unsigned short* hi = base + (size_t)wi * 131072;
    unsigned short* lo = hi + 65536;
    float4 v = ((const float4*)w)[idx];
    float f[4] = {v.x, v.y, v.z, v.w};
    short4v hv, lv;
    #pragma unroll
    for (int e = 0; e < 4; ++e) {
        unsigned short h = f2bf(f[e]);
        float rem = f[e] - bf2f(h);
        hv[e] = (short)h;
        lv[e] = (short)f2bf(rem);
    }
    *(short4v*)(hi + idx * 4) = hv;
    *(short4v*)(lo + idx * 4) = lv;
}

// ---------------- split-bf16 MFMA GEMM: r15 structure + reg-staged double buffer (T14) ----------------
// 512 thr, 128x256 tile. Per K-step: write prefetched regs -> LDS, issue next step's
// global loads (latency hides under this step's ds_read+MFMA), then compute.

__global__ __launch_bounds__(512, 4) void mfma_gemm_k(
    const float* __restrict__ AF,
    const unsigned short* __restrict__ Ah0, const unsigned short* __restrict__ Al0,
    const unsigned short* __restrict__ Wh0, const unsigned short* __restrict__ Wl0,
    const unsigned short* __restrict__ Ah1, const unsigned short* __restrict__ Al1,
    const unsigned short* __restrict__ Wh1, const unsigned short* __restrict__ Wl1,
    const float* __restrict__ bias,
    float* __restrict__ outF, unsigned short* __restrict__ outHi, unsigned short* __restrict__ outLo,
    signed char* __restrict__ outI8, float* __restrict__ outSc,
    const float* __restrict__ W4f, const float* __restrict__ b4f, float* __restrict__ outFinal,
    int nRows, int relu, int dual)
{
    __shared__ short Ahs[128 * LDP];
    __shared__ short Als[128 * LDP];
    __shared__ short Bhs[256 * LDP];
    __shared__ short Bls[256 * LDP];

    const int tid  = threadIdx.x;
    const int lane = tid & 63;
    const int wv   = tid >> 6;
    const int wm   = wv >> 2, wn = wv & 3;
    const int lrow = lane & 15, kg = lane >> 4;
    const int row0 = blockIdx.x * 128;

    const int sr = tid >> 2, sc = tid & 3;
    int agr = row0 + sr; if (agr >= nRows) agr = nRows - 1;

    floatx4 acc[4][4];
    #pragma unroll
    for (int i = 0; i < 4; ++i)
        #pragma unroll
        for (int j = 0; j < 4; ++j)
            acc[i][j] = (floatx4)0.0f;

    const int nstep = (dual ? 2 : 1) * 8;

    // prefetch registers
    short8v pAh, pAl, pB0h, pB0l, pB1h, pB1l;
    float4 pF0, pF1;

    auto LOADSTEP = [&](int st) {
        const int pass = st >> 3;
        const int k0 = (st & 7) * 32;
        const unsigned short* __restrict__ Ah = pass ? Ah1 : Ah0;
        const unsigned short* __restrict__ Al = pass ? Al1 : Al0;
        const unsigned short* __restrict__ Wh = pass ? Wh1 : Wh0;
        const unsigned short* __restrict__ Wl = pass ? Wl1 : Wl0;
        if ((pass == 0) && (AF != nullptr)) {
            const float* paf = AF + (size_t)agr * HDIM + k0 + sc * 8;
            pF0 = *(const float4*)paf;
            pF1 = *(const float4*)(paf + 4);
        } else {
            size_t ga = (size_t)agr * HDIM + k0 + sc * 8;
            pAh = *(const short8v*)(Ah + ga);
            pAl = *(const short8v*)(Al + ga);
        }
        {
            int br = tid >> 2, bc = tid & 3;             // q=0
            size_t gb = (size_t)br * HDIM + k0 + bc * 8;
            pB0h = *(const short8v*)(Wh + gb);
            pB0l = *(const short8v*)(Wl + gb);
        }
        {
            int idx = tid + 512;                          // q=1
            int br = idx >> 2, bc = idx & 3;
            size_t gb = (size_t)br * HDIM + k0 + bc * 8;
            pB1h = *(const short8v*)(Wh + gb);
            pB1l = *(const short8v*)(Wl + gb);
        }
    };

    LOADSTEP(0);
    for (int st = 0; st < nstep; ++st) {
        const bool f32A = ((st >> 3) == 0) && (AF != nullptr);
        __syncthreads();                      // previous step's LDS reads complete
        // write prefetched tile -> LDS
        if (f32A) {
            float f[8] = {pF0.x, pF0.y, pF0.z, pF0.w, pF1.x, pF1.y, pF1.z, pF1.w};
            short8v hv, lv;
            #pragma unroll
            for (int e = 0; e < 8; ++e) {
                unsigned short h = f2bf(f[e]);
                float rem = f[e] - bf2f(h);
                hv[e] = (short)h;
                lv[e] = (short)f2bf(rem);
            }
            *(short8v*)(Ahs + sr * LDP + sc * 8) = hv;
            *(short8v*)(Als + sr * LDP + sc * 8) = lv;
        } else {
            *(short8v*)(Ahs + sr * LDP + sc * 8) = pAh;
            *(short8v*)(Als + sr * LDP + sc * 8) = pAl;
        }
        {
            int br = tid >> 2, bc = tid & 3;
            *(short8v*)(Bhs + br * LDP + bc * 8) = pB0h;
            *(short8v*)(Bls + br * LDP + bc * 8) = pB0l;
        }
        {
            int idx = tid + 512;
            int br = idx >> 2, bc = idx & 3;
            *(short8v*)(Bhs + br * LDP + bc * 8) = pB1h;
            *(short8v*)(Bls + br * LDP + bc * 8) = pB1l;
        }
        // issue next step's global loads (latency hidden under this step's compute)
        if (st + 1 < nstep) LOADSTEP(st + 1);
        __syncthreads();                      // LDS writes visible

        short8v ahf[4], alf[4];
        #pragma unroll
        for (int fm = 0; fm < 4; ++fm) {
            int ra = (wm * 64 + fm * 16 + lrow) * LDP + kg * 8;
            ahf[fm] = *(const short8v*)(Ahs + ra);
            alf[fm] = *(const short8v*)(Als + ra);
        }
        #pragma unroll
        for (int fn = 0; fn < 4; ++fn) {
            int rb = (wn * 64 + fn * 16 + lrow) * LDP + kg * 8;
            short8v bh = *(const short8v*)(Bhs + rb);
            short8v bl = *(const short8v*)(Bls + rb);
            #pragma unroll
            for (int fm = 0; fm < 4; ++fm) {
                acc[fm][fn] = __builtin_amdgcn_mfma_f32_16x16x32_bf16(ahf[fm], bh, acc[fm][fn], 0, 0, 0);
                acc[fm][fn] = __builtin_amdgcn_mfma_f32_16x16x32_bf16(ahf[fm], bl, acc[fm][fn], 0, 0, 0);
                acc[fm][fn] = __builtin_amdgcn_mfma_f32_16x16x32_bf16(alf[fm], bh, acc[fm][fn], 0, 0, 0);
            }
        }
    }

    if (outFinal) {
        float w40[4], w41[4];
        #pragma unroll
        for (int fn = 0; fn < 4; ++fn) {
            int col = wn * 64 + fn * 16 + lrow;
            w40[fn] = W4f[col];
            w41[fn] = W4f[HDIM + col];
        }
        float p0[4][4], p1[4][4];
        #pragma unroll
        for (int fm = 0; fm < 4; ++fm)
            #pragma unroll
            for (int r = 0; r < 4; ++r) { p0[fm][r] = 0.f; p1[fm][r] = 0.f; }
        #pragma unroll
        for (int fn = 0; fn < 4; ++fn) {
            int col = wn * 64 + fn * 16 + lrow;
            float bv = bias[col];
            #pragma unroll
            for (int fm = 0; fm < 4; ++fm)
                #pragma unroll
                for (int r = 0; r < 4; ++r) {
                    float v = fmaxf(acc[fm][fn][r] + bv, 0.0f);
                    p0[fm][r] = fmaf(v, w40[fn], p0[fm][r]);
                    p1[fm][r] = fmaf(v, w41[fn], p1[fm][r]);
                }
        }
        #pragma unroll
        for (int fm = 0; fm < 4; ++fm)
            #pragma unroll
            for (int r = 0; r < 4; ++r) {
                #pragma unroll
                for (int m = 1; m < 16; m <<= 1) {
                    p0[fm][r] += __shfl_xor(p0[fm][r], m, 64);
                    p1[fm][r] += __shfl_xor(p1[fm][r], m, 64);
                }
            }
        __syncthreads();
        float* red = (float*)Ahs;
        if (lrow == 0) {
            #pragma unroll
            for (int fm = 0; fm < 4; ++fm)
                #pragma unroll
                for (int r = 0; r < 4; ++r) {
                    int rl = wm * 64 + fm * 16 + kg * 4 + r;
                    red[(wn * 128 + rl) * 2 + 0] = p0[fm][r];
                    red[(wn * 128 + rl) * 2 + 1] = p1[fm][r];
                }
        }
        __syncthreads();
        if (tid < 256) {
            int rl = tid >> 1, j = tid & 1;
            int grow = row0 + rl;
            if (grow < nRows) {
                float s = b4f[j]
                        + red[(0 * 128 + rl) * 2 + j] + red[(1 * 128 + rl) * 2 + j]
                        + red[(2 * 128 + rl) * 2 + j] + red[(3 * 128 + rl) * 2 + j];
                outFinal[(size_t)grow * 2 + j] = s;
            }
        }
        return;
    }

    // epilogue pass 1: write fp32/bf16-pair outputs, track per-row absmax
    float vmax[4][4];
    #pragma unroll
    for (int fm = 0; fm < 4; ++fm)
        #pragma unroll
        for (int r = 0; r < 4; ++r) vmax[fm][r] = 0.0f;
    #pragma unroll
    for (int fn = 0; fn < 4; ++fn) {
        int col = wn * 64 + fn * 16 + lrow;
        float bv = bias[col];
        #pragma unroll
        for (int fm = 0; fm < 4; ++fm) {
            #pragma unroll
            for (int r = 0; r < 4; ++r) {
                float v = acc[fm][fn][r] + bv;
                if (relu) v = fmaxf(v, 0.0f);
                vmax[fm][r] = fmaxf(vmax[fm][r], fabsf(v));
                int grow = row0 + wm * 64 + fm * 16 + kg * 4 + r;
                if (grow < nRows) {
                    size_t o = (size_t)grow * HDIM + col;
                    if (outF) outF[o] = v;
                    if (outHi) {
                        unsigned short h = f2bf(v);
                        outHi[o] = h;
                        outLo[o] = f2bf(v - bf2f(h));
                    }
                }
            }
        }
    }

    // epilogue pass 2: int8 shadow with per-row scale (for the gather kernel)
    if (outI8) {
        #pragma unroll
        for (int fm = 0; fm < 4; ++fm)
            #pragma unroll
            for (int r = 0; r < 4; ++r) {
                #pragma unroll
                for (int m = 1; m < 16; m <<= 1)
                    vmax[fm][r] = fmaxf(vmax[fm][r], __shfl_xor(vmax[fm][r], m, 64));
            }
        __syncthreads();
        float* wmax = (float*)Ahs;
        if (lrow == 0) {
            #pragma unroll
            for (int fm = 0; fm < 4; ++fm)
                #pragma unroll
                for (int r = 0; r < 4; ++r) {
                    int rl = wm * 64 + fm * 16 + kg * 4 + r;
                    wmax[wn * 128 + rl] = vmax[fm][r];
                }
        }
        __syncthreads();
        #pragma unroll
        for (int fm = 0; fm < 4; ++fm) {
            #pragma unroll
            for (int r = 0; r < 4; ++r) {
                int rl = wm * 64 + fm * 16 + kg * 4 + r;
                int grow = row0 + rl;
                float rmax = fmaxf(fmaxf(wmax[rl], wmax[128 + rl]),
                                   fmaxf(wmax[256 + rl], wmax[384 + rl]));
                float inv = (rmax > 0.0f) ? (127.0f / rmax) : 0.0f;
                if (grow < nRows) {
                    #pragma unroll
                    for (int fn = 0; fn < 4; ++fn) {
                        int col = wn * 64 + fn * 16 + lrow;
                        float v = acc[fm][fn][r] + bias[col];
                        if (relu) v = fmaxf(v, 0.0f);
                        outI8[(size_t)grow * HDIM + col] = (signed char)(int)rintf(v * inv);
                    }
                    if (wn == 0 && lrow == 0) outSc[grow] = rmax * (1.0f / 127.0f);
                }
            }
        }
    }
}

// ---------------- sparse aggregation: int8 gather + per-row scale, band-sorted ----------------

#define ACCQ1(m)                                                                 \
    {                                                                            \
        unsigned pv = *(const unsigned*)(hq + (size_t)m.x * HDIM + lane * 4);    \
        float wq = __int_as_float(m.y) * hs[m.x];                                \
        a0 = fmaf(wq, (float)((int)(pv << 24) >> 24), a0);                       \
        a1 = fmaf(wq, (float)((int)(pv << 16) >> 24), a1);                       \
        a2 = fmaf(wq, (float)((int)(pv << 8) >> 24), a2);                        \
        a3 = fmaf(wq, (float)((int)pv >> 24), a3);                               \
    }

#define ACCQ4(m0, m1, m2, m3) { ACCQ1(m0); ACCQ1(m1); ACCQ1(m2); ACCQ1(m3); }

__global__ __launch_bounds__(256) void aggregate_k(
    const signed char* __restrict__ hq, const float* __restrict__ hs,
    const int2* __restrict__ csr, const int* __restrict__ offs,
    unsigned short* __restrict__ outHi, unsigned short* __restrict__ outLo)
{
    __shared__ float red[4][256];
    __shared__ int2 sorted[256];
    __shared__ unsigned bins[NBAND];
    __shared__ unsigned cur[NBAND];

    const int n = blockIdx.x;
    const int tid = threadIdx.x;
    const int w = tid >> 6;
    const int lane = tid & 63;
    const int start = offs[n], end = offs[n + 1];
    const int deg = end - start;

    float a0 = 0.f, a1 = 0.f, a2 = 0.f, a3 = 0.f;

    if (deg <= 256) {
        if (tid < NBAND) { bins[tid] = 0u; }
        __syncthreads();
        int2 my; int myband = 0;
        if (tid < deg) {
            my = csr[start + tid];
            myband = my.x >> 12;
            atomicAdd(&bins[myband], 1u);
        }
        __syncthreads();
        if (tid == 0) {
            unsigned run = 0;
            #pragma unroll
            for (int b = 0; b < NBAND; ++b) { unsigned c = bins[b]; cur[b] = run; run += c; }
        }
        __syncthreads();
        if (tid < deg) {
            unsigned pos = atomicAdd(&cur[myband], 1u);
            sorted[pos] = my;
        }
        __syncthreads();

        int e = w;
        for (; e + 12 < deg; e += 16) {
            int2 m0 = sorted[e], m1 = sorted[e + 4], m2 = sorted[e + 8], m3 = sorted[e + 12];
            ACCQ4(m0, m1, m2, m3);
        }
        for (; e < deg; e += 4) {
            int2 m = sorted[e];
            ACCQ1(m);
        }
    } else {
        int e = start + w;
        for (; e + 12 < end; e += 16) {
            int2 m0 = csr[e], m1 = csr[e + 4], m2 = csr[e + 8], m3 = csr[e + 12];
            ACCQ4(m0, m1, m2, m3);
        }
        for (; e < end; e += 4) {
            int2 m = csr[e];
            ACCQ1(m);
        }
    }

    red[w][lane * 4 + 0] = a0;
    red[w][lane * 4 + 1] = a1;
    red[w][lane * 4 + 2] = a2;
    red[w][lane * 4 + 3] = a3;
    __syncthreads();

    const int t = threadIdx.x;
    float s = red[0][t] + red[1][t] + red[2][t] + red[3][t];
    size_t o = (size_t)n * HDIM + t;
    unsigned short h = f2bf(s);
    outHi[o] = h;
    outLo[o] = f2bf(s - bf2f(h));
}

// ---------------- launcher (r15 structure) ----------------

extern "C" void kernel_launch(void* const* d_in, const int* in_sizes, int n_in,
                              void* d_out, int out_size, void* d_ws, size_t ws_size,
                              hipStream_t stream) {
    const float* x   = (const float*)d_in[0];
    const int*   ei  = (const int*)d_in[1];
    const float* W1  = (const float*)d_in[2];
    const float* b1  = (const float*)d_in[3];
    const float* W2  = (const float*)d_in[4];
    const float* b2  = (const float*)d_in[5];
    const float* W3  = (const float*)d_in[6];
    const float* b3  = (const float*)d_in[7];
    const float* W4  = (const float*)d_in[8];
    const float* b4  = (const float*)d_in[9];
    const float* T10 = (const float*)d_in[10];
    const float* T11 = (const float*)d_in[11];
    const float* cb1 = (const float*)d_in[12];
    const float* T20 = (const float*)d_in[13];
    const float* T21 = (const float*)d_in[14];
    const float* cb2 = (const float*)d_in[15];

    const int nN = in_sizes[0] / HDIM;   // 50000 (must be <= 50048)
    const int nE = in_sizes[1] / 2;      // 1600000
    const int* src = ei;
    const int* dst = ei + nE;

    char* p = (char*)d_ws;
    auto alloc = [&](size_t bytes) { void* r = (void*)p; p += (bytes + 255) & ~(size_t)255; return r; };
    float* dis     = (float*)alloc((size_t)nN * 4);
    int*   tmp     = (int*)alloc((size_t)nN * 4);
    int*   bsums   = (int*)alloc(1024 * 4);
    int*   offs    = (int*)alloc((size_t)(nN + 1) * 4);
    int2*  csr     = (int2*)alloc((size_t)nE * 8);
    unsigned int* degS = (unsigned int*)alloc((size_t)NHB * NBINB);
    unsigned int* cntS = (unsigned int*)alloc((size_t)NHB * NBINB);
    const size_t NH = (size_t)nN * HDIM;
    unsigned short* Xh  = (unsigned short*)alloc(NH * 4);  unsigned short* Xl  = Xh + NH;
    unsigned short* Ahp = (unsigned short*)alloc(NH * 4);  unsigned short* Alp = Ahp + NH;
    unsigned short* Bhp = (unsigned short*)alloc(NH * 4);  unsigned short* Blp = Bhp + NH;
    unsigned short* Dhp = (unsigned short*)alloc(NH * 4);  unsigned short* Dlp = Dhp + NH;
    signed char*    i8b = (signed char*)alloc(NH);          // int8 shadow (reused B then D)
    float*          scb = (float*)alloc((size_t)nN * 4);    // per-row scale (reused)
    unsigned short* wsp = (unsigned short*)alloc((size_t)7 * 131072 * 2);

    float* out = (float*)d_out;
    const int nbN = (nN + 255) / 256;   // 196
    const int gb  = (nN + 127) / 128;   // 391

    // CSR + norm build (no global atomics anywhere)
    hist_k<<<2 * NHB, 512, 0, stream>>>(src, dst, degS, cntS, nE);
    reduce_k<<<nbN, 256, 0, stream>>>((const unsigned char*)degS, (unsigned char*)cntS,
                                      dis, tmp, bsums, nN);
    scan3_k<<<nbN, 256, 0, stream>>>(tmp, bsums, offs, nN, nE, nbN);
    fill_k<<<NHB, 512, 0, stream>>>(src, dst, dis, offs, cntS, csr, nE);

    // weight splits
    WPtrs wp; wp.w[0]=W1; wp.w[1]=W2; wp.w[2]=T10; wp.w[3]=T11; wp.w[4]=T20; wp.w[5]=T21; wp.w[6]=W3;
    wsplit_all_k<<<7 * 64, 256, 0, stream>>>(wp, wsp);
    unsigned short* wh[7]; unsigned short* wl[7];
    for (int i = 0; i < 7; ++i) { wh[i] = wsp + (size_t)i * 131072; wl[i] = wh[i] + 65536; }

    // h1 = relu(x@W1+b1) -> A   (x converted in-stage)
    mfma_gemm_k<<<gb, 512, 0, stream>>>(x, nullptr, nullptr, wh[0], wl[0],
                                        nullptr, nullptr, nullptr, nullptr,
                                        b1, nullptr, Ahp, Alp, nullptr, nullptr,
                                        nullptr, nullptr, nullptr, nN, 1, 0);
    // h2 = relu(A@W2+b2) -> B (+ int8 shadow for agg1)
    mfma_gemm_k<<<gb, 512, 0, stream>>>(nullptr, Ahp, Alp, wh[1], wl[1],
                                        nullptr, nullptr, nullptr, nullptr,
                                        b2, nullptr, Bhp, Blp, i8b, scb,
                                        nullptr, nullptr, nullptr, nN, 1, 0);

    // conv1: t1 = agg(int8(B)) -> X ; h3 = B@T10 + X@T11 + cb1 -> D (+ int8 shadow for agg2)
    aggregate_k<<<nN, 256, 0, stream>>>(i8b, scb, csr, offs, Xh, Xl);
    mfma_gemm_k<<<gb, 512, 0, stream>>>(nullptr, Bhp, Blp, wh[2], wl[2],
                                        Xh, Xl, wh[3], wl[3],
                                        cb1, nullptr, Dhp, Dlp, i8b, scb,
                                        nullptr, nullptr, nullptr, nN, 0, 1);

    // conv2: t2 = agg(int8(D)) -> A ; h4 = D@T20 + A@T21 + cb2 -> B
    aggregate_k<<<nN, 256, 0, stream>>>(i8b, scb, csr, offs, Ahp, Alp);
    mfma_gemm_k<<<gb, 512, 0, stream>>>(nullptr, Dhp, Dlp, wh[4], wl[4],
                                        Ahp, Alp, wh[5], wl[5],
                                        cb2, nullptr, Bhp, Blp, nullptr, nullptr,
                                        nullptr, nullptr, nullptr, nN, 0, 1);

    // out = relu(B@W3+b3) @ W4^T + b4   (fused final)
    mfma_gemm_k<<<gb, 512, 0, stream>>>(nullptr, Bhp, Blp, wh[6], wl[6],
                                        nullptr, nullptr, nullptr, nullptr,
                                        b3, nullptr, nullptr, nullptr, nullptr, nullptr,
                                        W4, b4, out, nN, 1, 0);
}

// Round 19
// 589.865 us; speedup vs baseline: 1.6200x; 1.6200x over previous
//
#include <hip/hip_runtime.h>

#define HDIM 256
#define NHB 256          // chunks for histogram/fill (chunk = nE/NHB = 6250)
#define NBINB 50048      // bins rounded to 64: covers nN <= 50048 nodes (u8 bins)
#define NBINW (NBINB/4)  // 12512 u32 words = 50 KB LDS
#define NBAND 16         // src band = src >> 12
#define LDP 40

typedef __attribute__((ext_vector_type(8))) short short8v;
typedef __attribute__((ext_vector_type(4))) short short4v;
typedef __attribute__((ext_vector_type(4))) float floatx4;

static __device__ __forceinline__ unsigned short f2bf(float f) {
    union { float f; unsigned u; } c; c.f = f;
    unsigned u = c.u;
    unsigned r = u + 0x7FFFu + ((u >> 16) & 1u);   // RNE
    return (unsigned short)(r >> 16);
}
static __device__ __forceinline__ float bf2f(unsigned short h) {
    union { unsigned u; float f; } c; c.u = ((unsigned)h) << 16;
    return c.f;
}

// ---------------- histogram: per-block private LDS u8 hist, no global atomics ----------------

__global__ __launch_bounds__(512) void hist_k(const int* __restrict__ src, const int* __restrict__ dst,
                                              unsigned int* __restrict__ degS, unsigned int* __restrict__ cntS,
                                              int nE) {
    __shared__ unsigned int h8[NBINW];
    const int tid = threadIdx.x;
    const int isDst = blockIdx.x >= NHB;
    const int bb = isDst ? blockIdx.x - NHB : blockIdx.x;
    const int* __restrict__ arr = isDst ? dst : src;
    unsigned int* __restrict__ outS = isDst ? cntS : degS;

    for (int i = tid; i < NBINW; i += 512) h8[i] = 0u;
    __syncthreads();
    const int chunk = (nE + NHB - 1) / NHB;
    const int e0 = bb * chunk;
    const int e1 = min(e0 + chunk, nE);
    for (int e = e0 + tid; e < e1; e += 512) {
        int n = arr[e];
        atomicAdd(&h8[n >> 2], 1u << ((n & 3) << 3));
    }
    __syncthreads();
    unsigned int* __restrict__ row = outS + (size_t)bb * NBINW;
    for (int i = tid; i < NBINW; i += 512) row[i] = h8[i];
}

// ---------------- reduce + scan1 ----------------

__global__ __launch_bounds__(256) void reduce_k(const unsigned char* __restrict__ degS,
                                                unsigned char* __restrict__ cntS,
                                                float* __restrict__ dis, int* __restrict__ tmp,
                                                int* __restrict__ bsums, int nN) {
    __shared__ int s[256];
    const int t = threadIdx.x;
    const int n = blockIdx.x * 256 + t;
    int run = 0;
    if (n < nN) {
        int d = 0;
        #pragma unroll 8
        for (int b = 0; b < NHB; ++b) d += degS[(size_t)b * NBINB + n];
        dis[n] = (d > 0) ? (1.0f / sqrtf((float)d)) : 0.0f;
        unsigned r = 0;
        #pragma unroll 4
        for (int b = 0; b < NHB; ++b) {
            size_t o = (size_t)b * NBINB + n;
            unsigned c = cntS[o];
            cntS[o] = (unsigned char)r;
            r += c;
        }
        run = (int)r;
    }
    s[t] = run; __syncthreads();
    #pragma unroll
    for (int off = 1; off < 256; off <<= 1) {
        int x = (t >= off) ? s[t - off] : 0;
        __syncthreads();
        s[t] += x;
        __syncthreads();
    }
    if (n < nN) tmp[n] = s[t];
    if (t == 255) bsums[blockIdx.x] = s[255];
}

// ---------------- scan3 (+ scan2 folded) ----------------

__global__ __launch_bounds__(256) void scan3_k(const int* __restrict__ tmp, const int* __restrict__ bsums,
                                               int* __restrict__ offs, int nN, int nE, int nb) {
    __shared__ int s[256];
    const int t = threadIdx.x;
    int v = (t < nb) ? bsums[t] : 0;
    s[t] = v; __syncthreads();
    #pragma unroll
    for (int off = 1; off < 256; off <<= 1) {
        int x = (t >= off) ? s[t - off] : 0;
        __syncthreads();
        s[t] += x;
        __syncthreads();
    }
    const int base = (blockIdx.x > 0) ? s[blockIdx.x - 1] : 0;
    __syncthreads();
    const int i = blockIdx.x * 256 + t;
    if (i < nN) {
        int prev = (t > 0) ? tmp[i - 1] : 0;
        offs[i] = base + prev;
    }
    if (i == nN - 1) offs[nN] = nE;
}

// ---------------- fill ----------------

__global__ __launch_bounds__(512) void fill_k(const int* __restrict__ src, const int* __restrict__ dst,
                                              const float* __restrict__ dis, const int* __restrict__ offs,
                                              const unsigned int* __restrict__ cntS,
                                              int2* __restrict__ csr, int nE) {
    __shared__ unsigned int cur8[NBINW];
    const int tid = threadIdx.x;
    const int bb = blockIdx.x;
    const unsigned int* __restrict__ baseRow = cntS + (size_t)bb * NBINW;
    for (int i = tid; i < NBINW; i += 512) cur8[i] = baseRow[i];
    __syncthreads();
    const int chunk = (nE + NHB - 1) / NHB;
    const int e0 = bb * chunk;
    const int e1 = min(e0 + chunk, nE);
    for (int e = e0 + tid; e < e1; e += 512) {
        int s = src[e], d = dst[e];
        unsigned sh = (unsigned)(d & 3) << 3;
        unsigned old = atomicAdd(&cur8[d >> 2], 1u << sh);
        unsigned c = (old >> sh) & 0xFFu;
        int p = offs[d] + (int)c;
        float w = -dis[s] * dis[d];
        csr[p] = make_int2(s, __float_as_int(w));
    }
}

// ---------------- weight splits ----------------

struct WPtrs { const float* w[7]; };
__global__ __launch_bounds__(256) void wsplit_all_k(WPtrs ws, unsigned short* __restrict__ base) {
    int wi = blockIdx.x >> 6;
    int idx = (blockIdx.x & 63) * 256 + threadIdx.x;
    const float* w = ws.w[wi];
    unsigned short* hi = base + (size_t)wi * 131072;
    unsigned short* lo = hi + 65536;
    float4 v = ((const float4*)w)[idx];
    float f[4] = {v.x, v.y, v.z, v.w};
    short4v hv, lv;
    #pragma unroll
    for (int e = 0; e < 4; ++e) {
        unsigned short h = f2bf(f[e]);
        float rem = f[e] - bf2f(h);
        hv[e] = (short)h;
        lv[e] = (short)f2bf(rem);
    }
    *(short4v*)(hi + idx * 4) = hv;
    *(short4v*)(lo + idx * 4) = lv;
}

// ---------------- split-bf16 MFMA GEMM (r15 structure) + optional int8 shadow epilogue ----------------

__global__ __launch_bounds__(512, 4) void mfma_gemm_k(
    const float* __restrict__ AF,
    const unsigned short* __restrict__ Ah0, const unsigned short* __restrict__ Al0,
    const unsigned short* __restrict__ Wh0, const unsigned short* __restrict__ Wl0,
    const unsigned short* __restrict__ Ah1, const unsigned short* __restrict__ Al1,
    const unsigned short* __restrict__ Wh1, const unsigned short* __restrict__ Wl1,
    const float* __restrict__ bias,
    float* __restrict__ outF, unsigned short* __restrict__ outHi, unsigned short* __restrict__ outLo,
    signed char* __restrict__ outI8, float* __restrict__ outSc,
    const float* __restrict__ W4f, const float* __restrict__ b4f, float* __restrict__ outFinal,
    int nRows, int relu, int dual)
{
    __shared__ short Ahs[128 * LDP];
    __shared__ short Als[128 * LDP];
    __shared__ short Bhs[256 * LDP];
    __shared__ short Bls[256 * LDP];

    const int tid  = threadIdx.x;
    const int lane = tid & 63;
    const int wv   = tid >> 6;
    const int wm   = wv >> 2, wn = wv & 3;
    const int lrow = lane & 15, kg = lane >> 4;
    const int row0 = blockIdx.x * 128;

    const int sr = tid >> 2, sc = tid & 3;
    int agr = row0 + sr; if (agr >= nRows) agr = nRows - 1;

    floatx4 acc[4][4];
    #pragma unroll
    for (int i = 0; i < 4; ++i)
        #pragma unroll
        for (int j = 0; j < 4; ++j)
            acc[i][j] = (floatx4)0.0f;

    const int npass = dual ? 2 : 1;
    for (int pass = 0; pass < npass; ++pass) {
        const unsigned short* __restrict__ Ah = pass ? Ah1 : Ah0;
        const unsigned short* __restrict__ Al = pass ? Al1 : Al0;
        const unsigned short* __restrict__ Wh = pass ? Wh1 : Wh0;
        const unsigned short* __restrict__ Wl = pass ? Wl1 : Wl0;
        const bool f32A = (pass == 0) && (AF != nullptr);
        for (int k0 = 0; k0 < HDIM; k0 += 32) {
            __syncthreads();
            if (f32A) {
                const float* pa = AF + (size_t)agr * HDIM + k0 + sc * 8;
                float4 v0 = *(const float4*)pa;
                float4 v1 = *(const float4*)(pa + 4);
                float f[8] = {v0.x, v0.y, v0.z, v0.w, v1.x, v1.y, v1.z, v1.w};
                short8v hv, lv;
                #pragma unroll
                for (int e = 0; e < 8; ++e) {
                    unsigned short h = f2bf(f[e]);
                    float rem = f[e] - bf2f(h);
                    hv[e] = (short)h;
                    lv[e] = (short)f2bf(rem);
                }
                *(short8v*)(Ahs + sr * LDP + sc * 8) = hv;
                *(short8v*)(Als + sr * LDP + sc * 8) = lv;
            } else {
                size_t ga = (size_t)agr * HDIM + k0 + sc * 8;
                *(short8v*)(Ahs + sr * LDP + sc * 8) = *(const short8v*)(Ah + ga);
                *(short8v*)(Als + sr * LDP + sc * 8) = *(const short8v*)(Al + ga);
            }
            #pragma unroll
            for (int q = 0; q < 2; ++q) {
                int idx = tid + q * 512;
                int br = idx >> 2, bc = idx & 3;
                size_t gb = (size_t)br * HDIM + k0 + bc * 8;
                *(short8v*)(Bhs + br * LDP + bc * 8) = *(const short8v*)(Wh + gb);
                *(short8v*)(Bls + br * LDP + bc * 8) = *(const short8v*)(Wl + gb);
            }
            __syncthreads();

            short8v ahf[4], alf[4];
            #pragma unroll
            for (int fm = 0; fm < 4; ++fm) {
                int ra = (wm * 64 + fm * 16 + lrow) * LDP + kg * 8;
                ahf[fm] = *(const short8v*)(Ahs + ra);
                alf[fm] = *(const short8v*)(Als + ra);
            }
            #pragma unroll
            for (int fn = 0; fn < 4; ++fn) {
                int rb = (wn * 64 + fn * 16 + lrow) * LDP + kg * 8;
                short8v bh = *(const short8v*)(Bhs + rb);
                short8v bl = *(const short8v*)(Bls + rb);
                #pragma unroll
                for (int fm = 0; fm < 4; ++fm) {
                    acc[fm][fn] = __builtin_amdgcn_mfma_f32_16x16x32_bf16(ahf[fm], bh, acc[fm][fn], 0, 0, 0);
                    acc[fm][fn] = __builtin_amdgcn_mfma_f32_16x16x32_bf16(ahf[fm], bl, acc[fm][fn], 0, 0, 0);
                    acc[fm][fn] = __builtin_amdgcn_mfma_f32_16x16x32_bf16(alf[fm], bh, acc[fm][fn], 0, 0, 0);
                }
            }
        }
    }

    if (outFinal) {
        float w40[4], w41[4];
        #pragma unroll
        for (int fn = 0; fn < 4; ++fn) {
            int col = wn * 64 + fn * 16 + lrow;
            w40[fn] = W4f[col];
            w41[fn] = W4f[HDIM + col];
        }
        float p0[4][4], p1[4][4];
        #pragma unroll
        for (int fm = 0; fm < 4; ++fm)
            #pragma unroll
            for (int r = 0; r < 4; ++r) { p0[fm][r] = 0.f; p1[fm][r] = 0.f; }
        #pragma unroll
        for (int fn = 0; fn < 4; ++fn) {
            int col = wn * 64 + fn * 16 + lrow;
            float bv = bias[col];
            #pragma unroll
            for (int fm = 0; fm < 4; ++fm)
                #pragma unroll
                for (int r = 0; r < 4; ++r) {
                    float v = fmaxf(acc[fm][fn][r] + bv, 0.0f);
                    p0[fm][r] = fmaf(v, w40[fn], p0[fm][r]);
                    p1[fm][r] = fmaf(v, w41[fn], p1[fm][r]);
                }
        }
        #pragma unroll
        for (int fm = 0; fm < 4; ++fm)
            #pragma unroll
            for (int r = 0; r < 4; ++r) {
                #pragma unroll
                for (int m = 1; m < 16; m <<= 1) {
                    p0[fm][r] += __shfl_xor(p0[fm][r], m, 64);
                    p1[fm][r] += __shfl_xor(p1[fm][r], m, 64);
                }
            }
        __syncthreads();
        float* red = (float*)Ahs;
        if (lrow == 0) {
            #pragma unroll
            for (int fm = 0; fm < 4; ++fm)
                #pragma unroll
                for (int r = 0; r < 4; ++r) {
                    int rl = wm * 64 + fm * 16 + kg * 4 + r;
                    red[(wn * 128 + rl) * 2 + 0] = p0[fm][r];
                    red[(wn * 128 + rl) * 2 + 1] = p1[fm][r];
                }
        }
        __syncthreads();
        if (tid < 256) {
            int rl = tid >> 1, j = tid & 1;
            int grow = row0 + rl;
            if (grow < nRows) {
                float s = b4f[j]
                        + red[(0 * 128 + rl) * 2 + j] + red[(1 * 128 + rl) * 2 + j]
                        + red[(2 * 128 + rl) * 2 + j] + red[(3 * 128 + rl) * 2 + j];
                outFinal[(size_t)grow * 2 + j] = s;
            }
        }
        return;
    }

    // epilogue pass 1: write fp32/bf16-pair outputs, track per-row absmax
    float vmax[4][4];
    #pragma unroll
    for (int fm = 0; fm < 4; ++fm)
        #pragma unroll
        for (int r = 0; r < 4; ++r) vmax[fm][r] = 0.0f;
    #pragma unroll
    for (int fn = 0; fn < 4; ++fn) {
        int col = wn * 64 + fn * 16 + lrow;
        float bv = bias[col];
        #pragma unroll
        for (int fm = 0; fm < 4; ++fm) {
            #pragma unroll
            for (int r = 0; r < 4; ++r) {
                float v = acc[fm][fn][r] + bv;
                if (relu) v = fmaxf(v, 0.0f);
                vmax[fm][r] = fmaxf(vmax[fm][r], fabsf(v));
                int grow = row0 + wm * 64 + fm * 16 + kg * 4 + r;
                if (grow < nRows) {
                    size_t o = (size_t)grow * HDIM + col;
                    if (outF) outF[o] = v;
                    if (outHi) {
                        unsigned short h = f2bf(v);
                        outHi[o] = h;
                        outLo[o] = f2bf(v - bf2f(h));
                    }
                }
            }
        }
    }

    // epilogue pass 2: int8 shadow with per-row scale (for the gather kernel)
    if (outI8) {
        #pragma unroll
        for (int fm = 0; fm < 4; ++fm)
            #pragma unroll
            for (int r = 0; r < 4; ++r) {
                #pragma unroll
                for (int m = 1; m < 16; m <<= 1)
                    vmax[fm][r] = fmaxf(vmax[fm][r], __shfl_xor(vmax[fm][r], m, 64));
            }
        __syncthreads();                       // tile LDS dead; reuse for wmax[4][128]
        float* wmax = (float*)Ahs;
        if (lrow == 0) {
            #pragma unroll
            for (int fm = 0; fm < 4; ++fm)
                #pragma unroll
                for (int r = 0; r < 4; ++r) {
                    int rl = wm * 64 + fm * 16 + kg * 4 + r;
                    wmax[wn * 128 + rl] = vmax[fm][r];
                }
        }
        __syncthreads();
        #pragma unroll
        for (int fm = 0; fm < 4; ++fm) {
            #pragma unroll
            for (int r = 0; r < 4; ++r) {
                int rl = wm * 64 + fm * 16 + kg * 4 + r;
                int grow = row0 + rl;
                float rmax = fmaxf(fmaxf(wmax[rl], wmax[128 + rl]),
                                   fmaxf(wmax[256 + rl], wmax[384 + rl]));
                float inv = (rmax > 0.0f) ? (127.0f / rmax) : 0.0f;
                if (grow < nRows) {
                    #pragma unroll
                    for (int fn = 0; fn < 4; ++fn) {
                        int col = wn * 64 + fn * 16 + lrow;
                        float v = acc[fm][fn][r] + bias[col];
                        if (relu) v = fmaxf(v, 0.0f);
                        outI8[(size_t)grow * HDIM + col] = (signed char)(int)rintf(v * inv);
                    }
                    if (wn == 0 && lrow == 0) outSc[grow] = rmax * (1.0f / 127.0f);
                }
            }
        }
    }
}

// ---------------- sparse aggregation: int8 gather + per-row scale, band-sorted ----------------

#define ACCQ1(m)                                                                 \
    {                                                                            \
        unsigned pv = *(const unsigned*)(hq + (size_t)m.x * HDIM + lane * 4);    \
        float wq = __int_as_float(m.y) * hs[m.x];                                \
        a0 = fmaf(wq, (float)((int)(pv << 24) >> 24), a0);                       \
        a1 = fmaf(wq, (float)((int)(pv << 16) >> 24), a1);                       \
        a2 = fmaf(wq, (float)((int)(pv << 8) >> 24), a2);                        \
        a3 = fmaf(wq, (float)((int)pv >> 24), a3);                               \
    }

#define ACCQ4(m0, m1, m2, m3) { ACCQ1(m0); ACCQ1(m1); ACCQ1(m2); ACCQ1(m3); }

__global__ __launch_bounds__(256) void aggregate_k(
    const signed char* __restrict__ hq, const float* __restrict__ hs,
    const int2* __restrict__ csr, const int* __restrict__ offs,
    unsigned short* __restrict__ outHi, unsigned short* __restrict__ outLo)
{
    __shared__ float red[4][256];
    __shared__ int2 sorted[256];
    __shared__ unsigned bins[NBAND];
    __shared__ unsigned cur[NBAND];

    const int n = blockIdx.x;
    const int tid = threadIdx.x;
    const int w = tid >> 6;
    const int lane = tid & 63;
    const int start = offs[n], end = offs[n + 1];
    const int deg = end - start;

    float a0 = 0.f, a1 = 0.f, a2 = 0.f, a3 = 0.f;

    if (deg <= 256) {
        if (tid < NBAND) { bins[tid] = 0u; }
        __syncthreads();
        int2 my; int myband = 0;
        if (tid < deg) {
            my = csr[start + tid];
            myband = my.x >> 12;
            atomicAdd(&bins[myband], 1u);
        }
        __syncthreads();
        if (tid == 0) {
            unsigned run = 0;
            #pragma unroll
            for (int b = 0; b < NBAND; ++b) { unsigned c = bins[b]; cur[b] = run; run += c; }
        }
        __syncthreads();
        if (tid < deg) {
            unsigned pos = atomicAdd(&cur[myband], 1u);
            sorted[pos] = my;
        }
        __syncthreads();

        int e = w;
        for (; e + 12 < deg; e += 16) {
            int2 m0 = sorted[e], m1 = sorted[e + 4], m2 = sorted[e + 8], m3 = sorted[e + 12];
            ACCQ4(m0, m1, m2, m3);
        }
        for (; e < deg; e += 4) {
            int2 m = sorted[e];
            ACCQ1(m);
        }
    } else {
        int e = start + w;
        for (; e + 12 < end; e += 16) {
            int2 m0 = csr[e], m1 = csr[e + 4], m2 = csr[e + 8], m3 = csr[e + 12];
            ACCQ4(m0, m1, m2, m3);
        }
        for (; e < end; e += 4) {
            int2 m = csr[e];
            ACCQ1(m);
        }
    }

    red[w][lane * 4 + 0] = a0;
    red[w][lane * 4 + 1] = a1;
    red[w][lane * 4 + 2] = a2;
    red[w][lane * 4 + 3] = a3;
    __syncthreads();

    const int t = threadIdx.x;
    float s = red[0][t] + red[1][t] + red[2][t] + red[3][t];
    size_t o = (size_t)n * HDIM + t;
    unsigned short h = f2bf(s);
    outHi[o] = h;
    outLo[o] = f2bf(s - bf2f(h));
}

// ---------------- launcher (r15 structure) ----------------

extern "C" void kernel_launch(void* const* d_in, const int* in_sizes, int n_in,
                              void* d_out, int out_size, void* d_ws, size_t ws_size,
                              hipStream_t stream) {
    const float* x   = (const float*)d_in[0];
    const int*   ei  = (const int*)d_in[1];
    const float* W1  = (const float*)d_in[2];
    const float* b1  = (const float*)d_in[3];
    const float* W2  = (const float*)d_in[4];
    const float* b2  = (const float*)d_in[5];
    const float* W3  = (const float*)d_in[6];
    const float* b3  = (const float*)d_in[7];
    const float* W4  = (const float*)d_in[8];
    const float* b4  = (const float*)d_in[9];
    const float* T10 = (const float*)d_in[10];
    const float* T11 = (const float*)d_in[11];
    const float* cb1 = (const float*)d_in[12];
    const float* T20 = (const float*)d_in[13];
    const float* T21 = (const float*)d_in[14];
    const float* cb2 = (const float*)d_in[15];

    const int nN = in_sizes[0] / HDIM;   // 50000 (must be <= 50048)
    const int nE = in_sizes[1] / 2;      // 1600000
    const int* src = ei;
    const int* dst = ei + nE;

    char* p = (char*)d_ws;
    auto alloc = [&](size_t bytes) { void* r = (void*)p; p += (bytes + 255) & ~(size_t)255; return r; };
    float* dis     = (float*)alloc((size_t)nN * 4);
    int*   tmp     = (int*)alloc((size_t)nN * 4);
    int*   bsums   = (int*)alloc(1024 * 4);
    int*   offs    = (int*)alloc((size_t)(nN + 1) * 4);
    int2*  csr     = (int2*)alloc((size_t)nE * 8);
    unsigned int* degS = (unsigned int*)alloc((size_t)NHB * NBINB);
    unsigned int* cntS = (unsigned int*)alloc((size_t)NHB * NBINB);
    const size_t NH = (size_t)nN * HDIM;
    unsigned short* Xh  = (unsigned short*)alloc(NH * 4);  unsigned short* Xl  = Xh + NH;
    unsigned short* Ahp = (unsigned short*)alloc(NH * 4);  unsigned short* Alp = Ahp + NH;
    unsigned short* Bhp = (unsigned short*)alloc(NH * 4);  unsigned short* Blp = Bhp + NH;
    unsigned short* Dhp = (unsigned short*)alloc(NH * 4);  unsigned short* Dlp = Dhp + NH;
    signed char*    i8b = (signed char*)alloc(NH);          // int8 shadow (reused B then D)
    float*          scb = (float*)alloc((size_t)nN * 4);    // per-row scale (reused)
    unsigned short* wsp = (unsigned short*)alloc((size_t)7 * 131072 * 2);

    float* out = (float*)d_out;
    const int nbN = (nN + 255) / 256;   // 196
    const int gb  = (nN + 127) / 128;   // 391

    // CSR + norm build (no global atomics anywhere)
    hist_k<<<2 * NHB, 512, 0, stream>>>(src, dst, degS, cntS, nE);
    reduce_k<<<nbN, 256, 0, stream>>>((const unsigned char*)degS, (unsigned char*)cntS,
                                      dis, tmp, bsums, nN);
    scan3_k<<<nbN, 256, 0, stream>>>(tmp, bsums, offs, nN, nE, nbN);
    fill_k<<<NHB, 512, 0, stream>>>(src, dst, dis, offs, cntS, csr, nE);

    // weight splits
    WPtrs wp; wp.w[0]=W1; wp.w[1]=W2; wp.w[2]=T10; wp.w[3]=T11; wp.w[4]=T20; wp.w[5]=T21; wp.w[6]=W3;
    wsplit_all_k<<<7 * 64, 256, 0, stream>>>(wp, wsp);
    unsigned short* wh[7]; unsigned short* wl[7];
    for (int i = 0; i < 7; ++i) { wh[i] = wsp + (size_t)i * 131072; wl[i] = wh[i] + 65536; }

    // h1 = relu(x@W1+b1) -> A   (x converted in-stage)
    mfma_gemm_k<<<gb, 512, 0, stream>>>(x, nullptr, nullptr, wh[0], wl[0],
                                        nullptr, nullptr, nullptr, nullptr,
                                        b1, nullptr, Ahp, Alp, nullptr, nullptr,
                                        nullptr, nullptr, nullptr, nN, 1, 0);
    // h2 = relu(A@W2+b2) -> B (+ int8 shadow for agg1)
    mfma_gemm_k<<<gb, 512, 0, stream>>>(nullptr, Ahp, Alp, wh[1], wl[1],
                                        nullptr, nullptr, nullptr, nullptr,
                                        b2, nullptr, Bhp, Blp, i8b, scb,
                                        nullptr, nullptr, nullptr, nN, 1, 0);

    // conv1: t1 = agg(int8(B)) -> X ; h3 = B@T10 + X@T11 + cb1 -> D (+ int8 shadow for agg2)
    aggregate_k<<<nN, 256, 0, stream>>>(i8b, scb, csr, offs, Xh, Xl);
    mfma_gemm_k<<<gb, 512, 0, stream>>>(nullptr, Bhp, Blp, wh[2], wl[2],
                                        Xh, Xl, wh[3], wl[3],
                                        cb1, nullptr, Dhp, Dlp, i8b, scb,
                                        nullptr, nullptr, nullptr, nN, 0, 1);

    // conv2: t2 = agg(int8(D)) -> A ; h4 = D@T20 + A@T21 + cb2 -> B
    aggregate_k<<<nN, 256, 0, stream>>>(i8b, scb, csr, offs, Ahp, Alp);
    mfma_gemm_k<<<gb, 512, 0, stream>>>(nullptr, Dhp, Dlp, wh[4], wl[4],
                                        Ahp, Alp, wh[5], wl[5],
                                        cb2, nullptr, Bhp, Blp, nullptr, nullptr,
                                        nullptr, nullptr, nullptr, nN, 0, 1);

    // out = relu(B@W3+b3) @ W4^T + b4   (fused final)
    mfma_gemm_k<<<gb, 512, 0, stream>>>(nullptr, Bhp, Blp, wh[6], wl[6],
                                        nullptr, nullptr, nullptr, nullptr,
                                        b3, nullptr, nullptr, nullptr, nullptr, nullptr,
                                        W4, b4, out, nN, 1, 0);
}